// Round 1
// baseline (165.019 us; speedup 1.0000x reference)
//
#include <hip/hip_runtime.h>
#include <math.h>

#define BB 32
#define TT 512
#define FF 512
#define HH 1024
#define CC 1000
#define NG 4
#define QQ (NG*HH)   // 4096 gate columns
#define JC 128       // j-chunk
#define NJ0 8        // h0 chunks (1024/128)
#define NJD 4        // data chunks (512/128)

// Stage 1: partial gate GEMM. grid = (QQ/256, NJ0+NJD), block = 256.
__global__ __launch_bounds__(256) void k_gemm_part(
    const float* __restrict__ data, const float* __restrict__ h0,
    const float* __restrict__ wf, const float* __restrict__ wi,
    const float* __restrict__ wc, const float* __restrict__ wo,
    float* __restrict__ hp, float* __restrict__ dp)
{
    __shared__ float lds[BB*JC];         // 16 KiB
    const int t  = threadIdx.x;
    const int bx = blockIdx.x;           // 16 column blocks of 256
    const int by = blockIdx.y;           // 12 j-chunks
    const int q  = bx*256 + t;           // global gate-column 0..4095
    const int gate = q >> 10;            // uniform per block (256 | 1024)
    const int k  = q & (HH-1);
    const float* w = (gate==0) ? wf : (gate==1) ? wi : (gate==2) ? wc : wo;

    if (by < NJ0) {
        // h0 contribution (batch-independent)
        const int j0 = by*JC;
        if (t < JC) lds[t] = h0[j0 + t];
        __syncthreads();
        float s = 0.f;
        #pragma unroll 8
        for (int j = 0; j < JC; ++j)
            s += lds[j] * w[(size_t)(j0 + j)*HH + k];
        hp[(size_t)by*QQ + q] = s;
    } else {
        // data[:,T-1,:] contribution
        const int jc  = by - NJ0;
        const int jj0 = jc*JC;
        for (int l = t; l < BB*JC; l += 256) {
            int b  = l >> 7;             // /JC
            int jj = l & (JC-1);
            lds[l] = data[(size_t)b*TT*FF + (size_t)(TT-1)*FF + jj0 + jj];
        }
        __syncthreads();
        float acc[BB];
        #pragma unroll
        for (int b = 0; b < BB; ++b) acc[b] = 0.f;
        for (int j = 0; j < JC; ++j) {
            float wv = w[(size_t)(HH + jj0 + j)*HH + k];
            #pragma unroll
            for (int b = 0; b < BB; ++b)
                acc[b] += lds[b*JC + j] * wv;
        }
        for (int b = 0; b < BB; ++b)
            dp[((size_t)(jc*BB + b))*QQ + q] = acc[b];
    }
}

// Stage 2: reduce partials, gate activations, cell update -> h_last.
// grid = (HH/256, BB), block = 256.
__global__ __launch_bounds__(256) void k_cell(
    const float* __restrict__ hp, const float* __restrict__ dp,
    const float* __restrict__ c0, float* __restrict__ hlast)
{
    const int t = threadIdx.x;
    const int k = blockIdx.x*256 + t;
    const int b = blockIdx.y;
    float g[4];
    #pragma unroll
    for (int gi = 0; gi < 4; ++gi) {
        const int q = gi*HH + k;
        float s = 0.f;
        #pragma unroll
        for (int jc = 0; jc < NJ0; ++jc) s += hp[(size_t)jc*QQ + q];
        #pragma unroll
        for (int jc = 0; jc < NJD; ++jc) s += dp[((size_t)(jc*BB + b))*QQ + q];
        g[gi] = s;
    }
    const float fg = 1.f/(1.f + expf(-g[0]));
    const float ig = 1.f/(1.f + expf(-g[1]));
    const float cg = tanhf(g[2]);
    const float og = 1.f/(1.f + expf(-g[3]));
    const float c  = fg*c0[k] + ig*cg;
    hlast[(size_t)b*HH + k] = og*tanhf(c);
}

// Stage 3: logits = relu(h @ fc_w^T + fc_b), then log_softmax per row.
// grid = (BB), block = 256.
__global__ __launch_bounds__(256) void k_fc(
    const float* __restrict__ hlast, const float* __restrict__ fcw,
    const float* __restrict__ fcb, float* __restrict__ out)
{
    __shared__ float hs[HH];
    __shared__ float red[8];
    const int b = blockIdx.x;
    const int t = threadIdx.x;
    for (int i = t; i < HH; i += 256) hs[i] = hlast[(size_t)b*HH + i];
    __syncthreads();

    float lg[4];
    float vmax = -1e30f;
    #pragma unroll
    for (int ci = 0; ci < 4; ++ci) {
        const int c = t + ci*256;
        float v = 0.f;
        if (c < CC) {
            const float4* wr = (const float4*)(fcw + (size_t)c*HH);
            float s = 0.f;
            #pragma unroll 4
            for (int k4 = 0; k4 < HH/4; ++k4) {
                float4 w4 = wr[k4];
                s += w4.x*hs[k4*4+0] + w4.y*hs[k4*4+1]
                   + w4.z*hs[k4*4+2] + w4.w*hs[k4*4+3];
            }
            v = fmaxf(s + fcb[c], 0.f);
            vmax = fmaxf(vmax, v);
        }
        lg[ci] = v;
    }

    // block-max
    for (int o = 32; o > 0; o >>= 1) vmax = fmaxf(vmax, __shfl_down(vmax, o, 64));
    const int lane = t & 63, wid = t >> 6;
    if (lane == 0) red[wid] = vmax;
    __syncthreads();
    if (t == 0) red[4] = fmaxf(fmaxf(red[0], red[1]), fmaxf(red[2], red[3]));
    __syncthreads();
    const float m = red[4];

    // block-sum of exp
    float se = 0.f;
    #pragma unroll
    for (int ci = 0; ci < 4; ++ci) {
        const int c = t + ci*256;
        if (c < CC) se += expf(lg[ci] - m);
    }
    for (int o = 32; o > 0; o >>= 1) se += __shfl_down(se, o, 64);
    if (lane == 0) red[wid] = se;
    __syncthreads();
    if (t == 0) red[5] = m + logf(red[0] + red[1] + red[2] + red[3]);
    __syncthreads();
    const float lse = red[5];

    #pragma unroll
    for (int ci = 0; ci < 4; ++ci) {
        const int c = t + ci*256;
        if (c < CC) out[(size_t)b*CC + c] = lg[ci] - lse;
    }
}

extern "C" void kernel_launch(void* const* d_in, const int* in_sizes, int n_in,
                              void* d_out, int out_size, void* d_ws, size_t ws_size,
                              hipStream_t stream) {
    const float* data = (const float*)d_in[0];
    const float* h0   = (const float*)d_in[1];
    const float* c0   = (const float*)d_in[2];
    const float* wf   = (const float*)d_in[3];
    const float* wi   = (const float*)d_in[4];
    const float* wc   = (const float*)d_in[5];
    const float* wo   = (const float*)d_in[6];
    const float* fcw  = (const float*)d_in[7];
    const float* fcb  = (const float*)d_in[8];
    float* out = (float*)d_out;

    float* ws = (float*)d_ws;
    float* hp = ws;                              // NJ0*QQ floats
    float* dp = hp + (size_t)NJ0*QQ;             // NJD*BB*QQ floats
    float* hl = dp + (size_t)NJD*BB*QQ;          // BB*HH floats

    k_gemm_part<<<dim3(QQ/256, NJ0+NJD), 256, 0, stream>>>(data, h0, wf, wi, wc, wo, hp, dp);
    k_cell<<<dim3(HH/256, BB), 256, 0, stream>>>(hp, dp, c0, hl);
    k_fc<<<dim3(BB), 256, 0, stream>>>(hl, fcw, fcb, out);
}

// Round 2
// 60.207 us; speedup vs baseline: 2.7408x; 2.7408x over previous
//
#include <hip/hip_runtime.h>
#include <math.h>

#define BB 32
#define TT 512
#define FF 512
#define HH 1024
#define CC 1000
#define NG 4
#define QQ (NG*HH)   // 4096 gate columns
#define JC 128       // j-chunk
#define NJ0 8        // h0 chunks (1024/128)
#define NJD 4        // data chunks (512/128)
#define FCB 8        // fc columns per block

// Stage 1: partial gate GEMM. grid = (QQ/256, NJ0+NJD), block = 256.
__global__ __launch_bounds__(256) void k_gemm_part(
    const float* __restrict__ data, const float* __restrict__ h0,
    const float* __restrict__ wf, const float* __restrict__ wi,
    const float* __restrict__ wc, const float* __restrict__ wo,
    float* __restrict__ hp, float* __restrict__ dp)
{
    __shared__ float lds[BB*JC];         // 16 KiB
    const int t  = threadIdx.x;
    const int bx = blockIdx.x;           // 16 column blocks of 256
    const int by = blockIdx.y;           // 12 j-chunks
    const int q  = bx*256 + t;           // global gate-column 0..4095
    const int gate = q >> 10;            // uniform per block (256 | 1024)
    const int k  = q & (HH-1);
    const float* w = (gate==0) ? wf : (gate==1) ? wi : (gate==2) ? wc : wo;

    if (by < NJ0) {
        // h0 contribution (batch-independent)
        const int j0 = by*JC;
        if (t < JC) lds[t] = h0[j0 + t];
        __syncthreads();
        float s = 0.f;
        #pragma unroll 8
        for (int j = 0; j < JC; ++j)
            s += lds[j] * w[(size_t)(j0 + j)*HH + k];
        hp[(size_t)by*QQ + q] = s;
    } else {
        // data[:,T-1,:] contribution
        const int jc  = by - NJ0;
        const int jj0 = jc*JC;
        for (int l = t; l < BB*JC; l += 256) {
            int b  = l >> 7;             // /JC
            int jj = l & (JC-1);
            lds[l] = data[(size_t)b*TT*FF + (size_t)(TT-1)*FF + jj0 + jj];
        }
        __syncthreads();
        float acc[BB];
        #pragma unroll
        for (int b = 0; b < BB; ++b) acc[b] = 0.f;
        for (int j = 0; j < JC; ++j) {
            float wv = w[(size_t)(HH + jj0 + j)*HH + k];
            #pragma unroll
            for (int b = 0; b < BB; ++b)
                acc[b] += lds[b*JC + j] * wv;
        }
        for (int b = 0; b < BB; ++b)
            dp[((size_t)(jc*BB + b))*QQ + q] = acc[b];
    }
}

// Stage 2: reduce partials, gate activations, cell update -> h_last.
// grid = (HH/256, BB), block = 256.
__global__ __launch_bounds__(256) void k_cell(
    const float* __restrict__ hp, const float* __restrict__ dp,
    const float* __restrict__ c0, float* __restrict__ hlast)
{
    const int t = threadIdx.x;
    const int k = blockIdx.x*256 + t;
    const int b = blockIdx.y;
    float g[4];
    #pragma unroll
    for (int gi = 0; gi < 4; ++gi) {
        const int q = gi*HH + k;
        float s = 0.f;
        #pragma unroll
        for (int jc = 0; jc < NJ0; ++jc) s += hp[(size_t)jc*QQ + q];
        #pragma unroll
        for (int jc = 0; jc < NJD; ++jc) s += dp[((size_t)(jc*BB + b))*QQ + q];
        g[gi] = s;
    }
    const float fg = 1.f/(1.f + expf(-g[0]));
    const float ig = 1.f/(1.f + expf(-g[1]));
    const float cg = tanhf(g[2]);
    const float og = 1.f/(1.f + expf(-g[3]));
    const float c  = fg*c0[k] + ig*cg;
    hlast[(size_t)b*HH + k] = og*tanhf(c);
}

// Stage 3a: logits = relu(h @ fc_w^T + fc_b). grid = (CC/FCB = 125), block = 256.
// Each block: FCB columns x 32 batches; one output per thread.
__global__ __launch_bounds__(256) void k_fc_gemm(
    const float* __restrict__ hlast, const float* __restrict__ fcw,
    const float* __restrict__ fcb, float* __restrict__ logits)
{
    __shared__ float hs[BB][257];     // padded: hs[b][k] read is conflict-free
    __shared__ float wl[FCB][257];    // wl[cl][k] read is a 32-lane broadcast
    const int t  = threadIdx.x;
    const int c0 = blockIdx.x * FCB;
    const int b  = t & 31;
    const int cl = t >> 5;
    const int c  = c0 + cl;
    float acc = 0.f;
    #pragma unroll
    for (int kc = 0; kc < HH/256; ++kc) {
        const int k0 = kc*256;
        // stage h chunk: 32 rows x 256 cols (float4 global loads, scalar LDS stores)
        for (int l = t; l < BB*64; l += 256) {
            const int bb = l >> 6, kk = l & 63;
            const float4 v = *(const float4*)(hlast + (size_t)bb*HH + k0 + kk*4);
            hs[bb][kk*4+0] = v.x; hs[bb][kk*4+1] = v.y;
            hs[bb][kk*4+2] = v.z; hs[bb][kk*4+3] = v.w;
        }
        // stage w chunk: FCB rows x 256 cols
        for (int l = t; l < FCB*64; l += 256) {
            const int cc = l >> 6, kk = l & 63;
            const float4 v = *(const float4*)(fcw + (size_t)(c0+cc)*HH + k0 + kk*4);
            wl[cc][kk*4+0] = v.x; wl[cc][kk*4+1] = v.y;
            wl[cc][kk*4+2] = v.z; wl[cc][kk*4+3] = v.w;
        }
        __syncthreads();
        #pragma unroll 16
        for (int k = 0; k < 256; ++k)
            acc += hs[b][k] * wl[cl][k];
        __syncthreads();
    }
    logits[(size_t)b*CC + c] = fmaxf(acc + fcb[c], 0.f);
}

// Stage 3b: log_softmax per batch row. grid = (BB), block = 256.
__global__ __launch_bounds__(256) void k_lsm(
    const float* __restrict__ logits, float* __restrict__ out)
{
    __shared__ float red[8];
    const int b = blockIdx.x, t = threadIdx.x;
    float v[4]; float vmax = -1e30f;
    #pragma unroll
    for (int ci = 0; ci < 4; ++ci) {
        const int c = t + ci*256;
        v[ci] = (c < CC) ? logits[(size_t)b*CC + c] : -1e30f;
        vmax = fmaxf(vmax, v[ci]);
    }
    for (int o = 32; o > 0; o >>= 1) vmax = fmaxf(vmax, __shfl_down(vmax, o, 64));
    const int lane = t & 63, wid = t >> 6;
    if (lane == 0) red[wid] = vmax;
    __syncthreads();
    if (t == 0) red[4] = fmaxf(fmaxf(red[0], red[1]), fmaxf(red[2], red[3]));
    __syncthreads();
    const float m = red[4];
    float se = 0.f;
    #pragma unroll
    for (int ci = 0; ci < 4; ++ci) {
        const int c = t + ci*256;
        if (c < CC) se += expf(v[ci] - m);
    }
    for (int o = 32; o > 0; o >>= 1) se += __shfl_down(se, o, 64);
    if (lane == 0) red[wid] = se;
    __syncthreads();
    if (t == 0) red[5] = m + logf(red[0] + red[1] + red[2] + red[3]);
    __syncthreads();
    const float lse = red[5];
    #pragma unroll
    for (int ci = 0; ci < 4; ++ci) {
        const int c = t + ci*256;
        if (c < CC) out[(size_t)b*CC + c] = v[ci] - lse;
    }
}

extern "C" void kernel_launch(void* const* d_in, const int* in_sizes, int n_in,
                              void* d_out, int out_size, void* d_ws, size_t ws_size,
                              hipStream_t stream) {
    const float* data = (const float*)d_in[0];
    const float* h0   = (const float*)d_in[1];
    const float* c0   = (const float*)d_in[2];
    const float* wf   = (const float*)d_in[3];
    const float* wi   = (const float*)d_in[4];
    const float* wc   = (const float*)d_in[5];
    const float* wo   = (const float*)d_in[6];
    const float* fcw  = (const float*)d_in[7];
    const float* fcb  = (const float*)d_in[8];
    float* out = (float*)d_out;

    float* ws = (float*)d_ws;
    float* hp = ws;                              // NJ0*QQ floats
    float* dp = hp + (size_t)NJ0*QQ;             // NJD*BB*QQ floats
    float* hl = dp + (size_t)NJD*BB*QQ;          // BB*HH floats
    float* lg = hl + (size_t)BB*HH;              // BB*CC floats

    k_gemm_part<<<dim3(QQ/256, NJ0+NJD), 256, 0, stream>>>(data, h0, wf, wi, wc, wo, hp, dp);
    k_cell<<<dim3(HH/256, BB), 256, 0, stream>>>(hp, dp, c0, hl);
    k_fc_gemm<<<dim3(CC/FCB), 256, 0, stream>>>(hl, fcw, fcb, lg);
    k_lsm<<<dim3(BB), 256, 0, stream>>>(lg, out);
}